// Round 4
// baseline (918.328 us; speedup 1.0000x reference)
//
#include <hip/hip_runtime.h>
#include <stdint.h>

// Causal dilated conv1d as a FUSED implicit bf16 MFMA GEMM.
//   out[b,o,t] = sum_{c,kk} W[o, c*4+kk] * x[b, c, t + 8*kk - 24]   (0 if idx<0)
// K-order kappa = kk*512 + c.  A = Wq[o][kappa] (bf16, prepacked by wperm_k).
// B tile is staged PER K-STEP directly from fp32 x (natural [c][t] layout):
// each thread loads a 4c x 4t fp32 patch (t-contiguous float4 per row),
// register-transposes, casts to bf16 (proven RNE helper), ds_writes
// Bs[n][kappa] rows.  No transposed intermediate tensor in HBM.

typedef unsigned short u16;
typedef unsigned int   u32;
typedef __attribute__((ext_vector_type(8))) __bf16 bf16x8;
typedef __attribute__((ext_vector_type(4))) float  floatx4;
typedef __attribute__((ext_vector_type(4))) float  f32x4;

#define NB   16
#define CIN  512
#define COUT 512
#define TT   8192
#define KTOT 2048          /* CIN * KW */
#define NKT  64            /* KTOT / 32 K-steps */

__device__ __forceinline__ u16 f2bf(float f) {
  // round-to-nearest-even bf16 (inputs are finite random normals) [proven]
  u32 u = __builtin_bit_cast(u32, f);
  u += 0x7fffu + ((u >> 16) & 1u);
  return (u16)(u >> 16);
}

__device__ __forceinline__ u32 pack2(float a, float b) {
  return (u32)f2bf(a) | ((u32)f2bf(b) << 16);
}

__device__ __forceinline__ void gl_lds16(const void* g, void* l) {
  // async 16B/lane global->LDS; LDS dest = wave-uniform base + lane*16
  __builtin_amdgcn_global_load_lds((__attribute__((address_space(1))) void*)(g),
                                   (__attribute__((address_space(3))) void*)(l),
                                   16, 0, 0);
}

// ---- Pass 1: W permute + cast  Wq[o][kk*512+c] = bf16(W[o][c*4+kk]) ------
__global__ __launch_bounds__(256) void wperm_k(const float* __restrict__ W,
                                               u16* __restrict__ Wq) {
  const int idx = blockIdx.x * 256 + threadIdx.x;   // o*512 + c, grid=1024
  const int o   = idx >> 9;
  const int c   = idx & 511;
  const f32x4 w = *(const f32x4*)(W + (size_t)idx * 4);
#pragma unroll
  for (int kk = 0; kk < 4; ++kk)
    Wq[((size_t)o * 4 + kk) * 512 + c] = f2bf(w[kk]);
}

// ---- Pass 2: fused GEMM (128x128x32 tile, 16x16x32 bf16 MFMA) ------------
// 1D grid, XCD-swizzled: the 4 m-blocks sharing a B strip get ids k,k+8,k+16,k+24
// -> same XCD under round-robin dispatch -> x-strip reuse in that XCD's L2.
__global__ __launch_bounds__(256) void conv_gemm_k(const u16* __restrict__ Wq,
                                                   const float* __restrict__ x,
                                                   float* __restrict__ out) {
  __shared__ u16 As[128 * 32];    // [m][kappa], 64B rows (gl_lds16-direct)
  __shared__ u16 Bs[128 * 32];    // [n][kappa], 64B rows (reg-staged transpose)

  const int tid  = threadIdx.x;
  const int lane = tid & 63;
  const int wave = tid >> 6;

  const int id   = blockIdx.x;              // 0..4095
  const int xcd  = id & 7;
  const int slot = id >> 3;
  const int m0   = (slot & 3) * 128;
  const int nb   = (slot >> 2) * 8 + xcd;   // 0..1023
  const int b    = nb >> 6;                 // 64 n-tiles per batch
  const int t0   = (nb & 63) * 128;

  // A staging: each wave stages 32 A-rows per K-step (2 gl_lds16 issues)
  const int lr = lane >> 2;                 // row within 16-row group
  const int lo = (lane & 3) * 16;           // byte offset within 64B row
  const char* Ag = (const char*)Wq + ((size_t)(m0 + wave * 32 + lr) * KTOT) * 2 + lo;
  char* Al = (char*)As + wave * 2048;

  // B staging geometry: thread owns 4 kappa (=4 c) x 4 n (=4 t)
  const int cgq = (tid & 7) * 4;            // kappa offset within K-step 0..28
  const int tg4 = (tid >> 3) * 4;           // n base 0..124
  const float* xb = x + (size_t)b * CIN * TT;

  // compute: 2x2 waves, each 64x64 = 4x4 MFMA tiles
  const int wm = (wave >> 1) * 64;
  const int wn = (wave & 1) * 64;
  const char* Af0 = (const char*)As + (wm + (lane & 15)) * 64 + (lane >> 4) * 16;
  const char* Bf0 = (const char*)Bs + (wn + (lane & 15)) * 64 + (lane >> 4) * 16;

  floatx4 acc[4][4];
#pragma unroll
  for (int i = 0; i < 4; ++i)
#pragma unroll
    for (int j = 0; j < 4; ++j) acc[i][j] = (floatx4)(0.0f);

  for (int kt = 0; kt < NKT; ++kt) {
    const int kk = kt >> 4;                 // tap index
    const int c0 = (kt & 15) * 32;          // channel offset of this K-step
    const int tb = t0 + tg4 + 8 * kk - 24;  // global t of this thread's n-base
    const float* rp = xb + (size_t)(c0 + cgq) * TT;

    // B loads first (older in vmcnt queue than the A DMA below)
    f32x4 vb0, vb1, vb2, vb3;
    if (tb >= 0) {
      vb0 = *(const f32x4*)(rp + (size_t)0 * TT + tb);
      vb1 = *(const f32x4*)(rp + (size_t)1 * TT + tb);
      vb2 = *(const f32x4*)(rp + (size_t)2 * TT + tb);
      vb3 = *(const f32x4*)(rp + (size_t)3 * TT + tb);
    } else {                                // only edge blocks (t0==0), kk<3
#pragma unroll
      for (int jj = 0; jj < 4; ++jj) {
        const bool ok = (tb + jj) >= 0;
        vb0[jj] = ok ? rp[(size_t)0 * TT + tb + jj] : 0.0f;
        vb1[jj] = ok ? rp[(size_t)1 * TT + tb + jj] : 0.0f;
        vb2[jj] = ok ? rp[(size_t)2 * TT + tb + jj] : 0.0f;
        vb3[jj] = ok ? rp[(size_t)3 * TT + tb + jj] : 0.0f;
      }
    }

    // A: async global->LDS
    gl_lds16(Ag + (size_t)kt * 64, Al);
    gl_lds16(Ag + (size_t)kt * 64 + 16 * 4096, Al + 1024);

    // B: register 4x4 transpose + proven RNE cast + LDS write
#pragma unroll
    for (int i = 0; i < 4; ++i) {
      uint2 w;
      w.x = pack2(vb0[i], vb1[i]);
      w.y = pack2(vb2[i], vb3[i]);
      *(uint2*)((char*)Bs + (size_t)(tg4 + i) * 64 + cgq * 2) = w;
    }
    __syncthreads();                        // drains A-DMA (vmcnt) + ds_writes

    bf16x8 af[4], bff[4];
#pragma unroll
    for (int i = 0; i < 4; ++i) af[i]  = *(const bf16x8*)(Af0 + i * 1024);
#pragma unroll
    for (int j = 0; j < 4; ++j) bff[j] = *(const bf16x8*)(Bf0 + j * 1024);
#pragma unroll
    for (int i = 0; i < 4; ++i)
#pragma unroll
      for (int j = 0; j < 4; ++j)
        acc[i][j] = __builtin_amdgcn_mfma_f32_16x16x32_bf16(af[i], bff[j], acc[i][j], 0, 0, 0);
    __syncthreads();                        // protect LDS for next staging
  }

  // epilogue: D layout col = lane&15, row = (lane>>4)*4 + reg  [m89-verified]
  const int dr = (lane >> 4) * 4;
  const int dc = lane & 15;
  float* outb = out + (size_t)b * COUT * TT;
#pragma unroll
  for (int i = 0; i < 4; ++i) {
#pragma unroll
    for (int j = 0; j < 4; ++j) {
      const int mm = m0 + wm + i * 16 + dr;
      const int nn = t0 + wn + j * 16 + dc;
      float* p = outb + (size_t)mm * TT + nn;
#pragma unroll
      for (int r = 0; r < 4; ++r) p[(size_t)r * TT] = acc[i][j][r];
    }
  }
}

extern "C" void kernel_launch(void* const* d_in, const int* in_sizes, int n_in,
                              void* d_out, int out_size, void* d_ws, size_t ws_size,
                              hipStream_t stream) {
  const float* x = (const float*)d_in[0];   // [16, 512, 8192]
  const float* W = (const float*)d_in[1];   // [512, 2048]
  float* out = (float*)d_out;               // [16, 512, 8192]

  // workspace: only Wq bf16 [512][2048] (2 MB). No transposed x tensor.
  u16* Wq = (u16*)d_ws;

  wperm_k    <<<dim3(1024), dim3(256), 0, stream>>>(W, Wq);
  conv_gemm_k<<<dim3(4096), dim3(256), 0, stream>>>(Wq, x, out);
}